// Round 1
// baseline (78.333 us; speedup 1.0000x reference)
//
#include <hip/hip_runtime.h>
#include <math.h>

#define D4 32          // 128 floats / 4 per float4
#define KTOT 256
#define TN 32          // nodes per block
#define TK 128         // centroids per block (K half)

__global__ __launch_bounds__(256) void scd_main(
    const float* __restrict__ node,
    const float* __restrict__ cw,
    const float* __restrict__ cptr,
    float* __restrict__ out,
    float* __restrict__ ws_part)
{
    __shared__ float4 xs[TN][D4];
    __shared__ float x2_s[TN];
    __shared__ float scale_s[TK];
    __shared__ float y2_s[TK];

    const int tid = threadIdx.x;
    const int bn = blockIdx.x >> 1;
    const int kh = blockIdx.x & 1;
    const int nb = bn * TN;
    const int kb = kh * TK;
    const float c = cptr[0];

    // ---- stage x tile into LDS (XOR-swizzled on float4 chunk index) ----
    const float4* nf4 = (const float4*)(node + (size_t)nb * 128);
    #pragma unroll
    for (int it = 0; it < (TN * D4) / 256; ++it) {
        int e = tid + 256 * it;
        int n = e >> 5;
        int cc = e & 31;
        xs[n][cc ^ ((n >> 2) & 7)] = nf4[e];
    }

    // ---- per-centroid projection scale + projected y2 for this K-half ----
    if (tid < TK) {
        int k = kb + tid;
        const float4* yr = (const float4*)(cw + (size_t)k * 128);
        float ss = 0.f;
        #pragma unroll 8
        for (int q = 0; q < D4; ++q) {
            float4 v = yr[q];
            ss += v.x * v.x + v.y * v.y + v.z * v.z + v.w * v.w;
        }
        float norm = fmaxf(sqrtf(ss), 1e-15f);
        float maxn = (1.0f - 4e-3f) / sqrtf(c);
        float sc = (norm > maxn) ? (maxn / norm) : 1.0f;
        scale_s[tid] = sc;
        y2_s[tid] = ss * sc * sc;
    }
    __syncthreads();

    // ---- x2 per node (8 threads per node) ----
    {
        int n = tid >> 3, q = tid & 7;
        float p = 0.f;
        #pragma unroll
        for (int cc = q * 4; cc < q * 4 + 4; ++cc) {
            float4 v = xs[n][cc ^ ((n >> 2) & 7)];
            p += v.x * v.x + v.y * v.y + v.z * v.z + v.w * v.w;
        }
        p += __shfl_xor(p, 1);
        p += __shfl_xor(p, 2);
        p += __shfl_xor(p, 4);
        if (q == 0) x2_s[n] = p;
    }
    __syncthreads();

    // ---- pairwise dot products: 4 nodes x 4 centroids per thread ----
    const int ng = tid & 7;   // node group 0..7  -> nodes 4*ng..4*ng+3
    const int kg = tid >> 3;  // k group 0..31    -> ks kb+4*kg..+3

    float acc[4][4];
    #pragma unroll
    for (int i = 0; i < 4; ++i)
        #pragma unroll
        for (int j = 0; j < 4; ++j) acc[i][j] = 0.f;

    const float* ybase = cw + (size_t)(kb + 4 * kg) * 128;

    #pragma unroll 4
    for (int cc = 0; cc < D4; ++cc) {
        float4 xv[4], yv[4];
        #pragma unroll
        for (int i = 0; i < 4; ++i) xv[i] = xs[4 * ng + i][cc ^ (ng & 7)];
        #pragma unroll
        for (int j = 0; j < 4; ++j) yv[j] = *(const float4*)(ybase + (size_t)j * 128 + cc * 4);
        #pragma unroll
        for (int i = 0; i < 4; ++i)
            #pragma unroll
            for (int j = 0; j < 4; ++j) {
                acc[i][j] += xv[i].x * yv[j].x;
                acc[i][j] += xv[i].y * yv[j].y;
                acc[i][j] += xv[i].z * yv[j].z;
                acc[i][j] += xv[i].w * yv[j].w;
            }
    }

    // ---- epilogue: hyperbolic sqdist + per-block column partials ----
    const float sqrt_c = sqrtf(c);
    const float two_over_sqrt_c = 2.0f / sqrt_c;
    float x2r[4];
    #pragma unroll
    for (int i = 0; i < 4; ++i) x2r[i] = x2_s[4 * ng + i];

    #pragma unroll
    for (int j = 0; j < 4; ++j) {
        int kk = 4 * kg + j;      // local k in [0,TK)
        int k = kb + kk;          // global k
        float sc = scale_s[kk];
        float y2 = y2_s[kk];
        float ksum = 0.f;
        #pragma unroll
        for (int i = 0; i < 4; ++i) {
            float x2 = x2r[i];
            float xy = -acc[i][j] * sc;   // dot(-x, y_proj)
            float a = 1.0f + 2.0f * c * xy + c * y2;
            float b = 1.0f - c * x2;
            float num2 = a * a * x2 + b * b * y2 + 2.0f * a * b * xy;
            num2 = fmaxf(num2, 0.0f);
            float den = 1.0f + 2.0f * c * xy + c * c * x2 * y2;
            den = fmaxf(den, 1e-15f);
            float z = sqrt_c * sqrtf(num2) / den;
            z = fminf(z, 0.99999994f);
            float at = 0.5f * logf((1.0f + z) / (1.0f - z));
            float d = two_over_sqrt_c * at;
            float s = d * d;
            out[KTOT + (size_t)(nb + 4 * ng + i) * KTOT + k] = s;
            ksum += s;
        }
        // reduce over the 8 node-groups (lanes tid = 8*kg + ng, ng in low 3 bits)
        ksum += __shfl_xor(ksum, 1);
        ksum += __shfl_xor(ksum, 2);
        ksum += __shfl_xor(ksum, 4);
        if (ng == 0) ws_part[(size_t)bn * KTOT + k] = ksum;
    }
}

__global__ __launch_bounds__(128) void scd_finalize(
    const float* __restrict__ ws_part,
    const float* __restrict__ mask,
    float* __restrict__ out,
    int nbn, int maskN)
{
    __shared__ float red[128];
    int tid = threadIdx.x;

    // sum(mask) — redundant per block, trivial
    float p = 0.f;
    const float4* m4 = (const float4*)mask;
    int m4n = maskN >> 2;
    for (int i = tid; i < m4n; i += 128) {
        float4 v = m4[i];
        p += v.x + v.y + v.z + v.w;
    }
    red[tid] = p;
    __syncthreads();
    for (int s = 64; s > 0; s >>= 1) {
        if (tid < s) red[tid] += red[tid + s];
        __syncthreads();
    }
    float inv = 1.0f / red[0];

    int k = blockIdx.x * 128 + tid;
    float s = 0.f;
    for (int b = 0; b < nbn; ++b) s += ws_part[(size_t)b * KTOT + k];
    out[k] = s * inv;
}

extern "C" void kernel_launch(void* const* d_in, const int* in_sizes, int n_in,
                              void* d_out, int out_size, void* d_ws, size_t ws_size,
                              hipStream_t stream) {
    const float* node = (const float*)d_in[0];
    const float* mask = (const float*)d_in[1];
    const float* cw   = (const float*)d_in[2];
    const float* cp   = (const float*)d_in[3];
    float* out = (float*)d_out;
    float* ws_part = (float*)d_ws;   // [N/TN][KTOT] f32 partial column sums

    int N = in_sizes[0] / 128;
    int maskN = in_sizes[1];
    int nbn = N / TN;

    scd_main<<<dim3(nbn * 2), 256, 0, stream>>>(node, cw, cp, out, ws_part);
    scd_finalize<<<dim3(2), 128, 0, stream>>>(ws_part, mask, out, nbn, maskN);
}

// Round 2
// 29.022 us; speedup vs baseline: 2.6991x; 2.6991x over previous
//
#include <hip/hip_runtime.h>
#include <math.h>

#define D4 32          // 128 floats / 4 per float4
#define KTOT 256
#define TN 32          // nodes per block
#define TK 128         // centroids per block (K half)

__global__ __launch_bounds__(256) void scd_main(
    const float* __restrict__ node,
    const float* __restrict__ cw,
    const float* __restrict__ cptr,
    float* __restrict__ out,
    float* __restrict__ ws_part)
{
    __shared__ float4 xs[TN][D4];
    __shared__ float x2_s[TN];
    __shared__ float scale_s[TK];
    __shared__ float y2_s[TK];

    const int tid = threadIdx.x;
    const int bn = blockIdx.x >> 1;
    const int kh = blockIdx.x & 1;
    const int nb = bn * TN;
    const int kb = kh * TK;
    const int nbn = gridDim.x >> 1;
    const float c = cptr[0];

    // ---- stage x tile into LDS (XOR-swizzled on float4 chunk index) ----
    const float4* nf4 = (const float4*)(node + (size_t)nb * 128);
    #pragma unroll
    for (int it = 0; it < (TN * D4) / 256; ++it) {
        int e = tid + 256 * it;
        int n = e >> 5;
        int cc = e & 31;
        xs[n][cc ^ ((n >> 2) & 7)] = nf4[e];
    }

    // ---- per-centroid projection scale + projected y2 for this K-half ----
    if (tid < TK) {
        int k = kb + tid;
        const float4* yr = (const float4*)(cw + (size_t)k * 128);
        float ss = 0.f;
        #pragma unroll 8
        for (int q = 0; q < D4; ++q) {
            float4 v = yr[q];
            ss += v.x * v.x + v.y * v.y + v.z * v.z + v.w * v.w;
        }
        float norm = fmaxf(sqrtf(ss), 1e-15f);
        float maxn = (1.0f - 4e-3f) / sqrtf(c);
        float sc = (norm > maxn) ? (maxn / norm) : 1.0f;
        scale_s[tid] = sc;
        y2_s[tid] = ss * sc * sc;
    }
    __syncthreads();

    // ---- x2 per node (8 threads per node) ----
    {
        int n = tid >> 3, q = tid & 7;
        float p = 0.f;
        #pragma unroll
        for (int cc = q * 4; cc < q * 4 + 4; ++cc) {
            float4 v = xs[n][cc ^ ((n >> 2) & 7)];
            p += v.x * v.x + v.y * v.y + v.z * v.z + v.w * v.w;
        }
        p += __shfl_xor(p, 1);
        p += __shfl_xor(p, 2);
        p += __shfl_xor(p, 4);
        if (q == 0) x2_s[n] = p;
    }
    __syncthreads();

    // ---- pairwise dot products: 4 nodes x 4 centroids per thread ----
    const int ng = tid & 7;   // node group 0..7  -> nodes 4*ng..4*ng+3
    const int kg = tid >> 3;  // k group 0..31    -> ks kb+4*kg..+3

    float acc[4][4];
    #pragma unroll
    for (int i = 0; i < 4; ++i)
        #pragma unroll
        for (int j = 0; j < 4; ++j) acc[i][j] = 0.f;

    const float* ybase = cw + (size_t)(kb + 4 * kg) * 128;

    #pragma unroll 4
    for (int cc = 0; cc < D4; ++cc) {
        float4 xv[4], yv[4];
        #pragma unroll
        for (int i = 0; i < 4; ++i) xv[i] = xs[4 * ng + i][cc ^ (ng & 7)];
        #pragma unroll
        for (int j = 0; j < 4; ++j) yv[j] = *(const float4*)(ybase + (size_t)j * 128 + cc * 4);
        #pragma unroll
        for (int i = 0; i < 4; ++i)
            #pragma unroll
            for (int j = 0; j < 4; ++j) {
                acc[i][j] += xv[i].x * yv[j].x;
                acc[i][j] += xv[i].y * yv[j].y;
                acc[i][j] += xv[i].z * yv[j].z;
                acc[i][j] += xv[i].w * yv[j].w;
            }
    }

    // ---- epilogue: hyperbolic sqdist + per-block column partials ----
    const float sqrt_c = sqrtf(c);
    const float two_over_sqrt_c = 2.0f / sqrt_c;
    float x2r[4];
    #pragma unroll
    for (int i = 0; i < 4; ++i) x2r[i] = x2_s[4 * ng + i];

    #pragma unroll
    for (int j = 0; j < 4; ++j) {
        int kk = 4 * kg + j;      // local k in [0,TK)
        int k = kb + kk;          // global k
        float sc = scale_s[kk];
        float y2 = y2_s[kk];
        float ksum = 0.f;
        #pragma unroll
        for (int i = 0; i < 4; ++i) {
            float x2 = x2r[i];
            float xy = -acc[i][j] * sc;   // dot(-x, y_proj)
            float a = 1.0f + 2.0f * c * xy + c * y2;
            float b = 1.0f - c * x2;
            float num2 = a * a * x2 + b * b * y2 + 2.0f * a * b * xy;
            num2 = fmaxf(num2, 0.0f);
            float den = 1.0f + 2.0f * c * xy + c * c * x2 * y2;
            den = fmaxf(den, 1e-15f);
            float z = sqrt_c * sqrtf(num2) / den;
            z = fminf(z, 0.99999994f);
            float at = 0.5f * logf((1.0f + z) / (1.0f - z));
            float d = two_over_sqrt_c * at;
            float s = d * d;
            out[KTOT + (size_t)(nb + 4 * ng + i) * KTOT + k] = s;
            ksum += s;
        }
        // reduce over the 8 node-groups (lanes tid = 8*kg + ng, ng in low 3 bits)
        ksum += __shfl_xor(ksum, 1);
        ksum += __shfl_xor(ksum, 2);
        ksum += __shfl_xor(ksum, 4);
        // transposed layout: ws_part[k][bn] for coalesced finalize reads
        if (ng == 0) ws_part[(size_t)k * nbn + bn] = ksum;
    }
}

// one block per centroid k; thread t owns partial row t (coalesced)
__global__ __launch_bounds__(256) void scd_finalize(
    const float* __restrict__ ws_part,
    const float* __restrict__ mask,
    float* __restrict__ out,
    int nbn, int maskN)
{
    __shared__ float red[256];
    const int tid = threadIdx.x;
    const int k = blockIdx.x;

    // sum(mask) — redundant per block (L2-resident after first touch)
    float p = 0.f;
    const float4* m4 = (const float4*)mask;
    int m4n = maskN >> 2;
    for (int i = tid; i < m4n; i += 256) {
        float4 v = m4[i];
        p += v.x + v.y + v.z + v.w;
    }

    // this k's partials, coalesced
    float s = 0.f;
    for (int b = tid; b < nbn; b += 256) s += ws_part[(size_t)k * nbn + b];

    red[tid] = p;
    __syncthreads();
    #pragma unroll
    for (int st = 128; st > 0; st >>= 1) {
        if (tid < st) red[tid] += red[tid + st];
        __syncthreads();
    }
    float msum = red[0];
    __syncthreads();

    red[tid] = s;
    __syncthreads();
    #pragma unroll
    for (int st = 128; st > 0; st >>= 1) {
        if (tid < st) red[tid] += red[tid + st];
        __syncthreads();
    }
    if (tid == 0) out[k] = red[0] / msum;
}

extern "C" void kernel_launch(void* const* d_in, const int* in_sizes, int n_in,
                              void* d_out, int out_size, void* d_ws, size_t ws_size,
                              hipStream_t stream) {
    const float* node = (const float*)d_in[0];
    const float* mask = (const float*)d_in[1];
    const float* cw   = (const float*)d_in[2];
    const float* cp   = (const float*)d_in[3];
    float* out = (float*)d_out;
    float* ws_part = (float*)d_ws;   // [KTOT][N/TN] f32 partial column sums (transposed)

    int N = in_sizes[0] / 128;
    int maskN = in_sizes[1];
    int nbn = N / TN;

    scd_main<<<dim3(nbn * 2), 256, 0, stream>>>(node, cw, cp, out, ws_part);
    scd_finalize<<<dim3(KTOT), 256, 0, stream>>>(ws_part, mask, out, nbn, maskN);
}